// Round 12
// baseline (187.856 us; speedup 1.0000x reference)
//
#include <hip/hip_runtime.h>
#include <hip/hip_bf16.h>

// Problem geometry
#define E_CNT  256
#define D_IN   15
#define HDIM   128
#define BATCH  8192
#define NPAIR  256                  // 256 pairs of 16-row chunks per expert
#define BPE    4                    // blocks per expert -> grid 1024; 512-thr blocks
#define NL2E   -1.44269504088896341f

typedef float f32x4 __attribute__((ext_vector_type(4)));
typedef short bf16x8 __attribute__((ext_vector_type(8)));
typedef unsigned int uint4v __attribute__((ext_vector_type(4)));

#define MFMA16(a, b, c) __builtin_amdgcn_mfma_f32_16x16x32_bf16((a), (b), (c), 0, 0, 0)
#define SCHED_FENCE() __builtin_amdgcn_sched_barrier(0)

// bf16 via round-half-up on the bit pattern (values finite here).
static __device__ inline unsigned short f2bf_rnd(float f) {
    unsigned u = __builtin_bit_cast(unsigned, f);
    return (unsigned short)((u + 0x8000u) >> 16);
}

// sigmoid with pre-scaled input az = -z*log2(e): s = rcp(1 + 2^az).
static __device__ inline float sg(float az) {
    float e = __builtin_amdgcn_exp2f(az);
    return __builtin_amdgcn_rcpf(1.0f + e);
}

// pack two floats to a bf16 pair (lo in low half), round-half-up: 3 VALU.
static __device__ inline unsigned pack2(float lo, float hi_) {
    unsigned a = __builtin_bit_cast(unsigned, lo) + 0x8000u;
    unsigned b = __builtin_bit_cast(unsigned, hi_) + 0x8000u;
#if __has_builtin(__builtin_amdgcn_perm)
    return __builtin_amdgcn_perm(b, a, 0x07060302u);   // D = {a.b2,a.b3,b.b2,b.b3}
#else
    return (a >> 16) | (b & 0xffff0000u);
#endif
}

// v_permlane32_swap_b32: a' = {a.g0,a.g1,b.g0,b.g1}, b' = {a.g2,a.g3,b.g2,b.g3}
static __device__ inline void pl32swap(unsigned &a, unsigned &b) {
#if __has_builtin(__builtin_amdgcn_permlane32_swap)
    auto r = __builtin_amdgcn_permlane32_swap(a, b, false, false);
    a = (unsigned)r[0];
    b = (unsigned)r[1];
#else
    asm volatile("v_permlane32_swap_b32 %0, %1" : "+v"(a), "+v"(b));
#endif
}

// v_permlane16_swap_b32: a' = {a.g0,b.g0,a.g2,b.g2}, b' = {a.g1,b.g1,a.g3,b.g3}
static __device__ inline void pl16swap(unsigned &a, unsigned &b) {
#if __has_builtin(__builtin_amdgcn_permlane16_swap)
    auto r = __builtin_amdgcn_permlane16_swap(a, b, false, false);
    a = (unsigned)r[0];
    b = (unsigned)r[1];
#else
    asm volatile("v_permlane16_swap_b32 %0, %1" : "+v"(a), "+v"(b));
#endif
}

static __device__ inline f32x4 zero4() { f32x4 z = {0.f, 0.f, 0.f, 0.f}; return z; }

// Redistribute two 16x16 C-tiles (pair-packed sigmoids) into one K=32 B-frag.
// (validated on-device in R8-R11: absmax 0.0078)
static __device__ inline bf16x8 mk_bfrag(unsigned X0, unsigned X1, unsigned Y0, unsigned Y1) {
    pl32swap(X0, Y0);
    pl32swap(X1, Y1);
    pl16swap(X0, Y0);
    pl16swap(X1, Y1);
    uint4v u = {X0, X1, Y0, Y1};
    return __builtin_bit_cast(bf16x8, u);
}

// x[B][15] f32 -> xbf[B][16] bf16 with slot 15 = 1.0 (b1 partner)
__global__ __launch_bounds__(256)
void prep_x_kernel(const float* __restrict__ x, unsigned short* __restrict__ xbf)
{
    int i = blockIdx.x * 256 + threadIdx.x;
    if (i >= BATCH * 16) return;
    int row = i >> 4, k = i & 15;
    float v = (k < D_IN) ? x[row * D_IN + k] : 1.0f;
    xbf[i] = f2bf_rnd(v);
}

// 16x16x32 MFMA MLP, dual-chunk, fragment-ordered compressed LDS (R10/R11-
// validated), re-geared to 512-thread blocks: 4 blocks/CU x 8 waves =
// 32 waves/CU (hw max), 8 waves/SIMD. VGPR demand measured 56 <= 64 cap.
// LDS 39.2KB x 4 = 156.7KB <= 160KB.
__global__ __launch_bounds__(512, 8)
void mlp256_kernel(const float* __restrict__ x, const unsigned short* __restrict__ xbf,
                   const float* __restrict__ W1, const float* __restrict__ b1,
                   const float* __restrict__ W2, const float* __restrict__ b2,
                   const float* __restrict__ W3, const float* __restrict__ b3,
                   float* __restrict__ dst, int use_xbf, int transposed)
{
    __shared__ __align__(16) unsigned short w2f[32 * 512];   // 32 KB
    __shared__ __align__(16) unsigned short w1f[8 * 256];    // 4 KB (lanes<32)
    __shared__ __align__(16) unsigned short b2f[8 * 128];    // 2 KB (q==0 lanes)
    __shared__ __align__(16) unsigned short w3f[128];        // 256 B (l15==0 lanes)
    __shared__ __align__(16) unsigned short zb[8];           // shared zero line

    const int tid  = threadIdx.x;
    const int wave = tid >> 6;          // 0..7
    const int lane = tid & 63;
    const int l15  = lane & 15;
    const int q    = lane >> 4;

    // grid = 1024: e = bid&255, rg = bid>>8 (0..3). Blocks e,e+256,e+512,e+768
    // share bid%8 -> same XCD under round-robin dispatch (W2 in one L2).
    const int bid = blockIdx.x;
    const int e   = bid & 255;
    const int rg  = bid >> 8;

    const float* w1p = W1 + e * (D_IN * HDIM);
    const float* b1p = b1 + e * HDIM;
    const float* w2p = W2 + e * (HDIM * HDIM);
    const float* b2p = b2 + e * HDIM;
    const float* w3p = W3 + e * HDIM;
    const float  b3v = b3[e];

    // ---- stage weights, fragment-ordered (prologue only; 512-thread strides) ----
    // W2: src (h,k) -> tile (h>>4)*4 + (k>>5), lane ((k>>3)&3)*16 + (h&15), j=k&7
    for (int i = tid; i < HDIM * HDIM; i += 512) {
        int h = i & 127, k = i >> 7;
        int t = ((h >> 4) << 2) + (k >> 5);
        int ln = (((k >> 3) & 3) << 4) + (h & 15);
        w2f[t * 512 + ln * 8 + (k & 7)] = f2bf_rnd(w2p[k * HDIM + h] * NL2E);
    }
    // W1 (+b1): 8 tiles x 32 lanes x 8; k = (ln>>4)*8 + j in 0..15
    for (int i = tid; i < 8 * 256; i += 512) {
        int t = i >> 8, ln = (i >> 3) & 31, j = i & 7;
        int k = (ln >> 4) * 8 + j, h = t * 16 + (ln & 15);
        float v = (k < D_IN) ? w1p[k * HDIM + h] : b1p[h];
        w1f[i] = f2bf_rnd(v * NL2E);
    }
    // b2: [ot][l15][8], j==0 carries the bias
    for (int i = tid; i < 8 * 128; i += 512) {
        int ot = i >> 7, l = (i >> 3) & 15, j = i & 7;
        b2f[i] = (j == 0) ? f2bf_rnd(b2p[ot * 16 + l] * NL2E) : (unsigned short)0;
    }
    // w3: [kb][q][8] unscaled; zero line
    if (tid < 128) w3f[tid] = f2bf_rnd(w3p[tid]);
    if (tid < 8)   zb[tid] = 0;

    bf16x8 ONEB;   // B[k==0]=1.0 (bias A-frag zero for k!=0 lanes -> don't-care)
#pragma unroll
    for (int j = 0; j < 8; ++j) ONEB[j] = 0;
    ONEB[0] = (short)0x3F80;

    __syncthreads();   // weights staged; waves independent from here

    // per-lane bases + selects (quarter-uniform; compile to v_cndmask on addr)
    const bool w1s = (lane < 32);
    const bool b2s = (q == 0);
    const bool w3s = (l15 == 0);
    const unsigned short* w1D = w1f + lane * 8;        // + t*256
    const unsigned short* w2B = w2f + lane * 8;        // + tile*512
    const unsigned short* b2D = b2f + l15 * 8;         // + ot*128
    const unsigned short* w3D = w3f + q * 8;           // + kb*32
    const int xoff = l15 * 16 + (q & 1) * 8;

    // pairs: slot = rg + 4*wave (0..31); p = slot + 32*j, 8 pairs per wave
    for (int p = rg + 4 * wave; p < NPAIR; p += 32) {
        const int cA = 2 * p, cB = 2 * p + 1;

        bf16x8 XA, XBv;
        if (use_xbf) {
            XA  = *reinterpret_cast<const bf16x8*>(xbf + (size_t)cA * 256 + xoff);
            XBv = *reinterpret_cast<const bf16x8*>(xbf + (size_t)cB * 256 + xoff);
        } else {
            const float* xa = x + (size_t)(cA * 16 + l15) * D_IN;
            const float* xb = x + (size_t)(cB * 16 + l15) * D_IN;
#pragma unroll
            for (int j = 0; j < 8; ++j) {
                int k = (q & 1) * 8 + j;
                XA[j]  = (short)f2bf_rnd((k < D_IN) ? xa[k] : 1.0f);
                XBv[j] = (short)f2bf_rnd((k < D_IN) ? xb[k] : 1.0f);
            }
        }

        // ---- layer 1, pairwise: two h-tiles -> one K=32 B-frag, both chunks ----
        bf16x8 H1A[4], H1B[4];
#pragma unroll
        for (int kb = 0; kb < 4; ++kb) {
            bf16x8 wa0 = *reinterpret_cast<const bf16x8*>(w1s ? (w1D + (2 * kb) * 256) : zb);
            f32x4 aa = MFMA16(wa0, XA,  zero4());
            f32x4 ba = MFMA16(wa0, XBv, zero4());
            bf16x8 wa1 = *reinterpret_cast<const bf16x8*>(w1s ? (w1D + (2 * kb + 1) * 256) : zb);
            f32x4 ab = MFMA16(wa1, XA,  zero4());
            f32x4 bb = MFMA16(wa1, XBv, zero4());
            unsigned pa0 = pack2(sg(aa[0]), sg(aa[1]));
            unsigned pa1 = pack2(sg(aa[2]), sg(aa[3]));
            unsigned pa2 = pack2(sg(ab[0]), sg(ab[1]));
            unsigned pa3 = pack2(sg(ab[2]), sg(ab[3]));
            H1A[kb] = mk_bfrag(pa0, pa1, pa2, pa3);
            unsigned pb0 = pack2(sg(ba[0]), sg(ba[1]));
            unsigned pb1 = pack2(sg(ba[2]), sg(ba[3]));
            unsigned pb2 = pack2(sg(bb[0]), sg(bb[1]));
            unsigned pb3 = pack2(sg(bb[2]), sg(bb[3]));
            H1B[kb] = mk_bfrag(pb0, pb1, pb2, pb3);
            SCHED_FENCE();
        }

        // ---- layer 2 + layer 3, pairwise: two out-tiles -> one L3 K-step ----
        f32x4 o3A = zero4(), o3B = zero4();
#pragma unroll
        for (int pt = 0; pt < 4; ++pt) {
            unsigned qa0, qa1, qa2, qa3, qb0, qb1, qb2, qb3;
            {
                const int ot = 2 * pt;
                bf16x8 wb = *reinterpret_cast<const bf16x8*>(b2s ? (b2D + ot * 128) : zb);
                f32x4 cA2 = MFMA16(wb, ONEB, zero4());
                f32x4 cB2 = MFMA16(wb, ONEB, zero4());
#pragma unroll
                for (int kb = 0; kb < 4; ++kb) {
                    bf16x8 wa = *reinterpret_cast<const bf16x8*>(w2B + (ot * 4 + kb) * 512);
                    cA2 = MFMA16(wa, H1A[kb], cA2);
                    cB2 = MFMA16(wa, H1B[kb], cB2);
                }
                qa0 = pack2(sg(cA2[0]), sg(cA2[1]));
                qa1 = pack2(sg(cA2[2]), sg(cA2[3]));
                qb0 = pack2(sg(cB2[0]), sg(cB2[1]));
                qb1 = pack2(sg(cB2[2]), sg(cB2[3]));
            }
            SCHED_FENCE();
            {
                const int ot = 2 * pt + 1;
                bf16x8 wb = *reinterpret_cast<const bf16x8*>(b2s ? (b2D + ot * 128) : zb);
                f32x4 cA2 = MFMA16(wb, ONEB, zero4());
                f32x4 cB2 = MFMA16(wb, ONEB, zero4());
#pragma unroll
                for (int kb = 0; kb < 4; ++kb) {
                    bf16x8 wa = *reinterpret_cast<const bf16x8*>(w2B + (ot * 4 + kb) * 512);
                    cA2 = MFMA16(wa, H1A[kb], cA2);
                    cB2 = MFMA16(wa, H1B[kb], cB2);
                }
                qa2 = pack2(sg(cA2[0]), sg(cA2[1]));
                qa3 = pack2(sg(cA2[2]), sg(cA2[3]));
                qb2 = pack2(sg(cB2[0]), sg(cB2[1]));
                qb3 = pack2(sg(cB2[2]), sg(cB2[3]));
            }
            bf16x8 w3a = *reinterpret_cast<const bf16x8*>(w3s ? (w3D + pt * 32) : zb);
            bf16x8 H2A = mk_bfrag(qa0, qa1, qa2, qa3);
            o3A = MFMA16(w3a, H2A, o3A);
            bf16x8 H2B = mk_bfrag(qb0, qb1, qb2, qb3);
            o3B = MFMA16(w3a, H2B, o3B);
            SCHED_FENCE();
        }

        if (q == 0) {   // output row 0 = quarter 0, reg 0; col = l15
            float vA = o3A[0] + b3v;
            float vB = o3B[0] + b3v;
            const int bbA = cA * 16 + l15;
            const int bbB = cB * 16 + l15;
            if (transposed) {
                dst[(size_t)e * BATCH + bbA] = vA;
                dst[(size_t)e * BATCH + bbB] = vB;
            } else {
                dst[(size_t)bbA * E_CNT + e] = vA;
                dst[(size_t)bbB * E_CNT + e] = vB;
            }
        }
    }
}

// wsT[e][b] (256 x 8192) -> out[b][e] (8192 x 256), 64x64 LDS tiles
__global__ __launch_bounds__(256)
void transpose_out_kernel(const float* __restrict__ wsT, float* __restrict__ out)
{
    __shared__ float tile[64][65];
    const int tx = threadIdx.x & 63;
    const int ty = threadIdx.x >> 6;
    const int b0 = blockIdx.x * 64;
    const int e0 = blockIdx.y * 64;
#pragma unroll
    for (int r = ty; r < 64; r += 4)
        tile[r][tx] = wsT[(size_t)(e0 + r) * BATCH + b0 + tx];
    __syncthreads();
#pragma unroll
    for (int r = ty; r < 64; r += 4)
        out[(size_t)(b0 + r) * E_CNT + e0 + tx] = tile[tx][r];
}

extern "C" void kernel_launch(void* const* d_in, const int* in_sizes, int n_in,
                              void* d_out, int out_size, void* d_ws, size_t ws_size,
                              hipStream_t stream) {
    const float* x  = (const float*)d_in[0];
    const float* W1 = (const float*)d_in[1];
    const float* b1 = (const float*)d_in[2];
    const float* W2 = (const float*)d_in[3];
    const float* b2 = (const float*)d_in[4];
    const float* W3 = (const float*)d_in[5];
    const float* b3 = (const float*)d_in[6];
    float* out = (float*)d_out;

    const size_t XBF_BYTES = (size_t)BATCH * 16 * sizeof(unsigned short);  // 256 KB
    const size_t WST_BYTES = (size_t)E_CNT * BATCH * sizeof(float);        // 8 MB

    const bool have_xbf = ws_size >= XBF_BYTES + WST_BYTES;
    const bool have_wst = ws_size >= WST_BYTES;

    unsigned short* xbf = (unsigned short*)d_ws;
    float* wsT = have_xbf ? (float*)((char*)d_ws + XBF_BYTES) : (float*)d_ws;

    if (have_xbf)
        prep_x_kernel<<<dim3((BATCH * 16 + 255) / 256), dim3(256), 0, stream>>>(x, xbf);

    if (have_wst) {
        mlp256_kernel<<<dim3(E_CNT * BPE), dim3(512), 0, stream>>>(
            x, xbf, W1, b1, W2, b2, W3, b3, wsT, have_xbf ? 1 : 0, 1);
        transpose_out_kernel<<<dim3(BATCH / 64, E_CNT / 64), dim3(256), 0, stream>>>(
            wsT, out);
    } else {
        mlp256_kernel<<<dim3(E_CNT * BPE), dim3(512), 0, stream>>>(
            x, xbf, W1, b1, W2, b2, W3, b3, out, 0, 0);
    }
}

// Round 13
// 172.832 us; speedup vs baseline: 1.0869x; 1.0869x over previous
//
#include <hip/hip_runtime.h>
#include <hip/hip_bf16.h>

// Problem geometry
#define E_CNT  256
#define D_IN   15
#define HDIM   128
#define BATCH  8192
#define NPAIR  256                  // 256 pairs of 16-row chunks per expert
#define BPE    3                    // blocks per expert -> grid 768; 512-thr blocks
#define NL2E   -1.44269504088896341f

typedef float f32x4 __attribute__((ext_vector_type(4)));
typedef short bf16x8 __attribute__((ext_vector_type(8)));
typedef unsigned int uint4v __attribute__((ext_vector_type(4)));

#define MFMA16(a, b, c) __builtin_amdgcn_mfma_f32_16x16x32_bf16((a), (b), (c), 0, 0, 0)
#define SCHED_FENCE() __builtin_amdgcn_sched_barrier(0)

// bf16 via round-half-up on the bit pattern (values finite here).
static __device__ inline unsigned short f2bf_rnd(float f) {
    unsigned u = __builtin_bit_cast(unsigned, f);
    return (unsigned short)((u + 0x8000u) >> 16);
}

// sigmoid with pre-scaled input az = -z*log2(e): s = rcp(1 + 2^az).
static __device__ inline float sg(float az) {
    float e = __builtin_amdgcn_exp2f(az);
    return __builtin_amdgcn_rcpf(1.0f + e);
}

// pack two floats to a bf16 pair (lo in low half), round-half-up: 3 VALU.
static __device__ inline unsigned pack2(float lo, float hi_) {
    unsigned a = __builtin_bit_cast(unsigned, lo) + 0x8000u;
    unsigned b = __builtin_bit_cast(unsigned, hi_) + 0x8000u;
#if __has_builtin(__builtin_amdgcn_perm)
    return __builtin_amdgcn_perm(b, a, 0x07060302u);   // D = {a.b2,a.b3,b.b2,b.b3}
#else
    return (a >> 16) | (b & 0xffff0000u);
#endif
}

// v_permlane32_swap_b32: a' = {a.g0,a.g1,b.g0,b.g1}, b' = {a.g2,a.g3,b.g2,b.g3}
static __device__ inline void pl32swap(unsigned &a, unsigned &b) {
#if __has_builtin(__builtin_amdgcn_permlane32_swap)
    auto r = __builtin_amdgcn_permlane32_swap(a, b, false, false);
    a = (unsigned)r[0];
    b = (unsigned)r[1];
#else
    asm volatile("v_permlane32_swap_b32 %0, %1" : "+v"(a), "+v"(b));
#endif
}

// v_permlane16_swap_b32: a' = {a.g0,b.g0,a.g2,b.g2}, b' = {a.g1,b.g1,a.g3,b.g3}
static __device__ inline void pl16swap(unsigned &a, unsigned &b) {
#if __has_builtin(__builtin_amdgcn_permlane16_swap)
    auto r = __builtin_amdgcn_permlane16_swap(a, b, false, false);
    a = (unsigned)r[0];
    b = (unsigned)r[1];
#else
    asm volatile("v_permlane16_swap_b32 %0, %1" : "+v"(a), "+v"(b));
#endif
}

static __device__ inline f32x4 zero4() { f32x4 z = {0.f, 0.f, 0.f, 0.f}; return z; }

// Redistribute two 16x16 C-tiles (pair-packed sigmoids) into one K=32 B-frag.
// (validated on-device in R8-R12: absmax 0.0078)
static __device__ inline bf16x8 mk_bfrag(unsigned X0, unsigned X1, unsigned Y0, unsigned Y1) {
    pl32swap(X0, Y0);
    pl32swap(X1, Y1);
    pl16swap(X0, Y0);
    pl16swap(X1, Y1);
    uint4v u = {X0, X1, Y0, Y1};
    return __builtin_bit_cast(bf16x8, u);
}

// x[B][15] f32 -> xbf[B][16] bf16 with slot 15 = 1.0 (b1 partner)
__global__ __launch_bounds__(256)
void prep_x_kernel(const float* __restrict__ x, unsigned short* __restrict__ xbf)
{
    int i = blockIdx.x * 256 + threadIdx.x;
    if (i >= BATCH * 16) return;
    int row = i >> 4, k = i & 15;
    float v = (k < D_IN) ? x[row * D_IN + k] : 1.0f;
    xbf[i] = f2bf_rnd(v);
}

// 16x16x32 MFMA MLP, dual-chunk, fragment-ordered compressed LDS (body
// byte-identical to R11's proven no-spill shape: 56 arch VGPR + ~24 acc = 80).
// Geared to 512-thread blocks at __launch_bounds__(512,6): VGPR cap ~80-84,
// 3 blocks/CU x 8 waves = 24 waves/CU = 6 waves/SIMD (+50% TLP vs R11).
// LDS 39.2KB x 3 = 117.6KB <= 160KB.
__global__ __launch_bounds__(512, 6)
void mlp256_kernel(const float* __restrict__ x, const unsigned short* __restrict__ xbf,
                   const float* __restrict__ W1, const float* __restrict__ b1,
                   const float* __restrict__ W2, const float* __restrict__ b2,
                   const float* __restrict__ W3, const float* __restrict__ b3,
                   float* __restrict__ dst, int use_xbf, int transposed)
{
    __shared__ __align__(16) unsigned short w2f[32 * 512];   // 32 KB
    __shared__ __align__(16) unsigned short w1f[8 * 256];    // 4 KB (lanes<32)
    __shared__ __align__(16) unsigned short b2f[8 * 128];    // 2 KB (q==0 lanes)
    __shared__ __align__(16) unsigned short w3f[128];        // 256 B (l15==0 lanes)
    __shared__ __align__(16) unsigned short zb[8];           // shared zero line

    const int tid  = threadIdx.x;
    const int wave = tid >> 6;          // 0..7
    const int lane = tid & 63;
    const int l15  = lane & 15;
    const int q    = lane >> 4;

    // grid = 768: e = bid&255, rg = bid>>8 (0..2). Blocks e, e+256, e+512 share
    // bid%8 -> same XCD under round-robin dispatch (W2 in one L2).
    const int bid = blockIdx.x;
    const int e   = bid & 255;
    const int rg  = bid >> 8;

    const float* w1p = W1 + e * (D_IN * HDIM);
    const float* b1p = b1 + e * HDIM;
    const float* w2p = W2 + e * (HDIM * HDIM);
    const float* b2p = b2 + e * HDIM;
    const float* w3p = W3 + e * HDIM;
    const float  b3v = b3[e];

    // ---- stage weights, fragment-ordered (prologue only; 512-thread strides) ----
    // W2: src (h,k) -> tile (h>>4)*4 + (k>>5), lane ((k>>3)&3)*16 + (h&15), j=k&7
    for (int i = tid; i < HDIM * HDIM; i += 512) {
        int h = i & 127, k = i >> 7;
        int t = ((h >> 4) << 2) + (k >> 5);
        int ln = (((k >> 3) & 3) << 4) + (h & 15);
        w2f[t * 512 + ln * 8 + (k & 7)] = f2bf_rnd(w2p[k * HDIM + h] * NL2E);
    }
    // W1 (+b1): 8 tiles x 32 lanes x 8; k = (ln>>4)*8 + j in 0..15
    for (int i = tid; i < 8 * 256; i += 512) {
        int t = i >> 8, ln = (i >> 3) & 31, j = i & 7;
        int k = (ln >> 4) * 8 + j, h = t * 16 + (ln & 15);
        float v = (k < D_IN) ? w1p[k * HDIM + h] : b1p[h];
        w1f[i] = f2bf_rnd(v * NL2E);
    }
    // b2: [ot][l15][8], j==0 carries the bias
    for (int i = tid; i < 8 * 128; i += 512) {
        int ot = i >> 7, l = (i >> 3) & 15, j = i & 7;
        b2f[i] = (j == 0) ? f2bf_rnd(b2p[ot * 16 + l] * NL2E) : (unsigned short)0;
    }
    // w3: [kb][q][8] unscaled; zero line
    if (tid < 128) w3f[tid] = f2bf_rnd(w3p[tid]);
    if (tid < 8)   zb[tid] = 0;

    bf16x8 ONEB;   // B[k==0]=1.0 (bias A-frag zero for k!=0 lanes -> don't-care)
#pragma unroll
    for (int j = 0; j < 8; ++j) ONEB[j] = 0;
    ONEB[0] = (short)0x3F80;

    __syncthreads();   // weights staged; waves independent from here

    // per-lane bases + selects (quarter-uniform; compile to v_cndmask on addr)
    const bool w1s = (lane < 32);
    const bool b2s = (q == 0);
    const bool w3s = (l15 == 0);
    const unsigned short* w1D = w1f + lane * 8;        // + t*256
    const unsigned short* w2B = w2f + lane * 8;        // + tile*512
    const unsigned short* b2D = b2f + l15 * 8;         // + ot*128
    const unsigned short* w3D = w3f + q * 8;           // + kb*32
    const int xoff = l15 * 16 + (q & 1) * 8;

    // pairs: slot = rg + 3*wave (0..23 bijective for rg<3, wave<8); stride 24
    for (int p = rg + 3 * wave; p < NPAIR; p += 24) {
        const int cA = 2 * p, cB = 2 * p + 1;

        bf16x8 XA, XBv;
        if (use_xbf) {
            XA  = *reinterpret_cast<const bf16x8*>(xbf + (size_t)cA * 256 + xoff);
            XBv = *reinterpret_cast<const bf16x8*>(xbf + (size_t)cB * 256 + xoff);
        } else {
            const float* xa = x + (size_t)(cA * 16 + l15) * D_IN;
            const float* xb = x + (size_t)(cB * 16 + l15) * D_IN;
#pragma unroll
            for (int j = 0; j < 8; ++j) {
                int k = (q & 1) * 8 + j;
                XA[j]  = (short)f2bf_rnd((k < D_IN) ? xa[k] : 1.0f);
                XBv[j] = (short)f2bf_rnd((k < D_IN) ? xb[k] : 1.0f);
            }
        }

        // ---- layer 1, pairwise: two h-tiles -> one K=32 B-frag, both chunks ----
        bf16x8 H1A[4], H1B[4];
#pragma unroll
        for (int kb = 0; kb < 4; ++kb) {
            bf16x8 wa0 = *reinterpret_cast<const bf16x8*>(w1s ? (w1D + (2 * kb) * 256) : zb);
            f32x4 aa = MFMA16(wa0, XA,  zero4());
            f32x4 ba = MFMA16(wa0, XBv, zero4());
            bf16x8 wa1 = *reinterpret_cast<const bf16x8*>(w1s ? (w1D + (2 * kb + 1) * 256) : zb);
            f32x4 ab = MFMA16(wa1, XA,  zero4());
            f32x4 bb = MFMA16(wa1, XBv, zero4());
            unsigned pa0 = pack2(sg(aa[0]), sg(aa[1]));
            unsigned pa1 = pack2(sg(aa[2]), sg(aa[3]));
            unsigned pa2 = pack2(sg(ab[0]), sg(ab[1]));
            unsigned pa3 = pack2(sg(ab[2]), sg(ab[3]));
            H1A[kb] = mk_bfrag(pa0, pa1, pa2, pa3);
            unsigned pb0 = pack2(sg(ba[0]), sg(ba[1]));
            unsigned pb1 = pack2(sg(ba[2]), sg(ba[3]));
            unsigned pb2 = pack2(sg(bb[0]), sg(bb[1]));
            unsigned pb3 = pack2(sg(bb[2]), sg(bb[3]));
            H1B[kb] = mk_bfrag(pb0, pb1, pb2, pb3);
            SCHED_FENCE();
        }

        // ---- layer 2 + layer 3, pairwise: two out-tiles -> one L3 K-step ----
        f32x4 o3A = zero4(), o3B = zero4();
#pragma unroll
        for (int pt = 0; pt < 4; ++pt) {
            unsigned qa0, qa1, qa2, qa3, qb0, qb1, qb2, qb3;
            {
                const int ot = 2 * pt;
                bf16x8 wb = *reinterpret_cast<const bf16x8*>(b2s ? (b2D + ot * 128) : zb);
                f32x4 cA2 = MFMA16(wb, ONEB, zero4());
                f32x4 cB2 = MFMA16(wb, ONEB, zero4());
#pragma unroll
                for (int kb = 0; kb < 4; ++kb) {
                    bf16x8 wa = *reinterpret_cast<const bf16x8*>(w2B + (ot * 4 + kb) * 512);
                    cA2 = MFMA16(wa, H1A[kb], cA2);
                    cB2 = MFMA16(wa, H1B[kb], cB2);
                }
                qa0 = pack2(sg(cA2[0]), sg(cA2[1]));
                qa1 = pack2(sg(cA2[2]), sg(cA2[3]));
                qb0 = pack2(sg(cB2[0]), sg(cB2[1]));
                qb1 = pack2(sg(cB2[2]), sg(cB2[3]));
            }
            SCHED_FENCE();
            {
                const int ot = 2 * pt + 1;
                bf16x8 wb = *reinterpret_cast<const bf16x8*>(b2s ? (b2D + ot * 128) : zb);
                f32x4 cA2 = MFMA16(wb, ONEB, zero4());
                f32x4 cB2 = MFMA16(wb, ONEB, zero4());
#pragma unroll
                for (int kb = 0; kb < 4; ++kb) {
                    bf16x8 wa = *reinterpret_cast<const bf16x8*>(w2B + (ot * 4 + kb) * 512);
                    cA2 = MFMA16(wa, H1A[kb], cA2);
                    cB2 = MFMA16(wa, H1B[kb], cB2);
                }
                qa2 = pack2(sg(cA2[0]), sg(cA2[1]));
                qa3 = pack2(sg(cA2[2]), sg(cA2[3]));
                qb2 = pack2(sg(cB2[0]), sg(cB2[1]));
                qb3 = pack2(sg(cB2[2]), sg(cB2[3]));
            }
            bf16x8 w3a = *reinterpret_cast<const bf16x8*>(w3s ? (w3D + pt * 32) : zb);
            bf16x8 H2A = mk_bfrag(qa0, qa1, qa2, qa3);
            o3A = MFMA16(w3a, H2A, o3A);
            bf16x8 H2B = mk_bfrag(qb0, qb1, qb2, qb3);
            o3B = MFMA16(w3a, H2B, o3B);
            SCHED_FENCE();
        }

        if (q == 0) {   // output row 0 = quarter 0, reg 0; col = l15
            float vA = o3A[0] + b3v;
            float vB = o3B[0] + b3v;
            const int bbA = cA * 16 + l15;
            const int bbB = cB * 16 + l15;
            if (transposed) {
                dst[(size_t)e * BATCH + bbA] = vA;
                dst[(size_t)e * BATCH + bbB] = vB;
            } else {
                dst[(size_t)bbA * E_CNT + e] = vA;
                dst[(size_t)bbB * E_CNT + e] = vB;
            }
        }
    }
}

// wsT[e][b] (256 x 8192) -> out[b][e] (8192 x 256), 64x64 LDS tiles
__global__ __launch_bounds__(256)
void transpose_out_kernel(const float* __restrict__ wsT, float* __restrict__ out)
{
    __shared__ float tile[64][65];
    const int tx = threadIdx.x & 63;
    const int ty = threadIdx.x >> 6;
    const int b0 = blockIdx.x * 64;
    const int e0 = blockIdx.y * 64;
#pragma unroll
    for (int r = ty; r < 64; r += 4)
        tile[r][tx] = wsT[(size_t)(e0 + r) * BATCH + b0 + tx];
    __syncthreads();
#pragma unroll
    for (int r = ty; r < 64; r += 4)
        out[(size_t)(b0 + r) * E_CNT + e0 + tx] = tile[tx][r];
}

extern "C" void kernel_launch(void* const* d_in, const int* in_sizes, int n_in,
                              void* d_out, int out_size, void* d_ws, size_t ws_size,
                              hipStream_t stream) {
    const float* x  = (const float*)d_in[0];
    const float* W1 = (const float*)d_in[1];
    const float* b1 = (const float*)d_in[2];
    const float* W2 = (const float*)d_in[3];
    const float* b2 = (const float*)d_in[4];
    const float* W3 = (const float*)d_in[5];
    const float* b3 = (const float*)d_in[6];
    float* out = (float*)d_out;

    const size_t XBF_BYTES = (size_t)BATCH * 16 * sizeof(unsigned short);  // 256 KB
    const size_t WST_BYTES = (size_t)E_CNT * BATCH * sizeof(float);        // 8 MB

    const bool have_xbf = ws_size >= XBF_BYTES + WST_BYTES;
    const bool have_wst = ws_size >= WST_BYTES;

    unsigned short* xbf = (unsigned short*)d_ws;
    float* wsT = have_xbf ? (float*)((char*)d_ws + XBF_BYTES) : (float*)d_ws;

    if (have_xbf)
        prep_x_kernel<<<dim3((BATCH * 16 + 255) / 256), dim3(256), 0, stream>>>(x, xbf);

    if (have_wst) {
        mlp256_kernel<<<dim3(E_CNT * BPE), dim3(512), 0, stream>>>(
            x, xbf, W1, b1, W2, b2, W3, b3, wsT, have_xbf ? 1 : 0, 1);
        transpose_out_kernel<<<dim3(BATCH / 64, E_CNT / 64), dim3(256), 0, stream>>>(
            wsT, out);
    } else {
        mlp256_kernel<<<dim3(E_CNT * BPE), dim3(512), 0, stream>>>(
            x, xbf, W1, b1, W2, b2, W3, b3, out, 0, 0);
    }
}

// Round 15
// 162.089 us; speedup vs baseline: 1.1590x; 1.0663x over previous
//
#include <hip/hip_runtime.h>
#include <hip/hip_bf16.h>

// Problem geometry
#define E_CNT  256
#define D_IN   15
#define HDIM   128
#define BATCH  8192
#define NPAIR  256                  // 256 pairs of 16-row chunks per expert
#define BPE    4                    // blocks per expert -> grid 1024, 4 blocks/CU
#define NL2E   -1.44269504088896341f

typedef float f32x4 __attribute__((ext_vector_type(4)));
typedef short bf16x8 __attribute__((ext_vector_type(8)));
typedef unsigned int uint4v __attribute__((ext_vector_type(4)));

#define MFMA16(a, b, c) __builtin_amdgcn_mfma_f32_16x16x32_bf16((a), (b), (c), 0, 0, 0)
#define SCHED_FENCE() __builtin_amdgcn_sched_barrier(0)

// bf16 via round-half-up on the bit pattern (values finite here).
static __device__ inline unsigned short f2bf_rnd(float f) {
    unsigned u = __builtin_bit_cast(unsigned, f);
    return (unsigned short)((u + 0x8000u) >> 16);
}

// sigmoid with pre-scaled input az = -z*log2(e): s = rcp(1 + 2^az).
static __device__ inline float sg(float az) {
    float e = __builtin_amdgcn_exp2f(az);
    return __builtin_amdgcn_rcpf(1.0f + e);
}

// pack two floats to a bf16 pair (lo in low half), round-half-up: 3 VALU.
// (NOT hand-written v_cvt_pk_bf16_f32: that asm corrupted results in R2/R14;
// guide m240 also warns against hand-writing it.)
static __device__ inline unsigned pack2(float lo, float hi_) {
    unsigned a = __builtin_bit_cast(unsigned, lo) + 0x8000u;
    unsigned b = __builtin_bit_cast(unsigned, hi_) + 0x8000u;
#if __has_builtin(__builtin_amdgcn_perm)
    return __builtin_amdgcn_perm(b, a, 0x07060302u);   // D = {a.b2,a.b3,b.b2,b.b3}
#else
    return (a >> 16) | (b & 0xffff0000u);
#endif
}

// v_permlane32_swap_b32: a' = {a.g0,a.g1,b.g0,b.g1}, b' = {a.g2,a.g3,b.g2,b.g3}
static __device__ inline void pl32swap(unsigned &a, unsigned &b) {
#if __has_builtin(__builtin_amdgcn_permlane32_swap)
    auto r = __builtin_amdgcn_permlane32_swap(a, b, false, false);
    a = (unsigned)r[0];
    b = (unsigned)r[1];
#else
    asm volatile("v_permlane32_swap_b32 %0, %1" : "+v"(a), "+v"(b));
#endif
}

// v_permlane16_swap_b32: a' = {a.g0,b.g0,a.g2,b.g2}, b' = {a.g1,b.g1,a.g3,b.g3}
static __device__ inline void pl16swap(unsigned &a, unsigned &b) {
#if __has_builtin(__builtin_amdgcn_permlane16_swap)
    auto r = __builtin_amdgcn_permlane16_swap(a, b, false, false);
    a = (unsigned)r[0];
    b = (unsigned)r[1];
#else
    asm volatile("v_permlane16_swap_b32 %0, %1" : "+v"(a), "+v"(b));
#endif
}

static __device__ inline f32x4 zero4() { f32x4 z = {0.f, 0.f, 0.f, 0.f}; return z; }

// Redistribute two 16x16 C-tiles (pair-packed sigmoids) into one K=32 B-frag.
// (validated on-device R8-R13: absmax 0.0078)
static __device__ inline bf16x8 mk_bfrag(unsigned X0, unsigned X1, unsigned Y0, unsigned Y1) {
    pl32swap(X0, Y0);
    pl32swap(X1, Y1);
    pl16swap(X0, Y0);
    pl16swap(X1, Y1);
    uint4v u = {X0, X1, Y0, Y1};
    return __builtin_bit_cast(bf16x8, u);
}

// x[B][15] f32 -> xbf[B][16] bf16 with slot 15 = 1.0 (b1 partner)
__global__ __launch_bounds__(256)
void prep_x_kernel(const float* __restrict__ x, unsigned short* __restrict__ xbf)
{
    int i = blockIdx.x * 256 + threadIdx.x;
    if (i >= BATCH * 16) return;
    int row = i >> 4, k = i & 15;
    float v = (k < D_IN) ? x[row * D_IN + k] : 1.0f;
    xbf[i] = f2bf_rnd(v);
}

// 16x16x32 MFMA MLP, dual-chunk, fragment-ordered compressed LDS (R11 config:
// 256 thr, (256,4), 4 blocks/CU = 4 waves/SIMD, no spill at cap 128).
// R15 = R11 body + two safe R14 deltas: b2 bias enters as the MFMA C-init
// read from an f32 LDS copy (kills 16 bias-MFMAs + 8 LDS reads per pair),
// and fences thinned 12->5 (scheduler overlaps sigmoid chains in the
// 48-reg margin). Packing stays integer round-half-up (proven).
__global__ __launch_bounds__(256, 4)
void mlp256_kernel(const float* __restrict__ x, const unsigned short* __restrict__ xbf,
                   const float* __restrict__ W1, const float* __restrict__ b1,
                   const float* __restrict__ W2, const float* __restrict__ b2,
                   const float* __restrict__ W3, const float* __restrict__ b3,
                   float* __restrict__ dst, int use_xbf, int transposed)
{
    __shared__ __align__(16) unsigned short w2f[32 * 512];   // 32 KB
    __shared__ __align__(16) unsigned short w1f[8 * 256];    // 4 KB (lanes<32)
    __shared__ __align__(16) float          b2l[128];        // 512 B (f32, scaled)
    __shared__ __align__(16) unsigned short w3f[128];        // 256 B (l15==0 lanes)
    __shared__ __align__(16) unsigned short zb[8];           // shared zero line

    const int tid  = threadIdx.x;
    const int wave = tid >> 6;
    const int lane = tid & 63;
    const int l15  = lane & 15;
    const int q    = lane >> 4;

    // grid = 1024: e = bid&255, rg = bid>>8 (0..3). Blocks e,e+256,e+512,e+768
    // share bid%8 -> same XCD under round-robin dispatch (W2 in one L2).
    const int bid = blockIdx.x;
    const int e   = bid & 255;
    const int rg  = bid >> 8;

    const float* w1p = W1 + e * (D_IN * HDIM);
    const float* b1p = b1 + e * HDIM;
    const float* w2p = W2 + e * (HDIM * HDIM);
    const float* b2p = b2 + e * HDIM;
    const float* w3p = W3 + e * HDIM;
    const float  b3v = b3[e];

    // ---- stage weights, fragment-ordered (prologue only) ----
    // W2: src (h,k) -> tile (h>>4)*4 + (k>>5), lane ((k>>3)&3)*16 + (h&15), j=k&7
    for (int i = tid; i < HDIM * HDIM; i += 256) {
        int h = i & 127, k = i >> 7;
        int t = ((h >> 4) << 2) + (k >> 5);
        int ln = (((k >> 3) & 3) << 4) + (h & 15);
        w2f[t * 512 + ln * 8 + (k & 7)] = f2bf_rnd(w2p[k * HDIM + h] * NL2E);
    }
    // W1 (+b1): 8 tiles x 32 lanes x 8; k = (ln>>4)*8 + j in 0..15
    for (int i = tid; i < 8 * 256; i += 256) {
        int t = i >> 8, ln = (i >> 3) & 31, j = i & 7;
        int k = (ln >> 4) * 8 + j, h = t * 16 + (ln & 15);
        float v = (k < D_IN) ? w1p[k * HDIM + h] : b1p[h];
        w1f[i] = f2bf_rnd(v * NL2E);
    }
    // b2 as f32 (scaled): accumulator C-init; w3: [kb][q][8] unscaled; zero line
    if (tid < 128) b2l[tid] = b2p[tid] * NL2E;
    if (tid < 128) w3f[tid] = f2bf_rnd(w3p[tid]);
    if (tid < 8)   zb[tid] = 0;

    __syncthreads();   // weights staged; waves independent from here

    // per-lane bases + selects (quarter-uniform; compile to v_cndmask on addr)
    const bool w1s = (lane < 32);
    const bool w3s = (l15 == 0);
    const unsigned short* w1D = w1f + lane * 8;        // + t*256
    const unsigned short* w2B = w2f + lane * 8;        // + tile*512
    const float*          b2D = b2l + q * 4;           // + ot*16 (l15-independent)
    const unsigned short* w3D = w3f + q * 8;           // + kb*32
    const int xoff = l15 * 16 + (q & 1) * 8;

    // pairs: slot = rg + 4*wave (0..15); p = slot + 16*j, 16 pairs per wave
    for (int p = rg + 4 * wave; p < NPAIR; p += 16) {
        const int cA = 2 * p, cB = 2 * p + 1;

        bf16x8 XA, XBv;
        if (use_xbf) {
            XA  = *reinterpret_cast<const bf16x8*>(xbf + (size_t)cA * 256 + xoff);
            XBv = *reinterpret_cast<const bf16x8*>(xbf + (size_t)cB * 256 + xoff);
        } else {
            const float* xa = x + (size_t)(cA * 16 + l15) * D_IN;
            const float* xb = x + (size_t)(cB * 16 + l15) * D_IN;
#pragma unroll
            for (int j = 0; j < 8; ++j) {
                int k = (q & 1) * 8 + j;
                XA[j]  = (short)f2bf_rnd((k < D_IN) ? xa[k] : 1.0f);
                XBv[j] = (short)f2bf_rnd((k < D_IN) ? xb[k] : 1.0f);
            }
        }

        // ---- layer 1, pairwise: two h-tiles -> one K=32 B-frag, both chunks ----
        bf16x8 H1A[4], H1B[4];
#pragma unroll
        for (int kb = 0; kb < 4; ++kb) {
            bf16x8 wa0 = *reinterpret_cast<const bf16x8*>(w1s ? (w1D + (2 * kb) * 256) : zb);
            f32x4 aa = MFMA16(wa0, XA,  zero4());
            f32x4 ba = MFMA16(wa0, XBv, zero4());
            bf16x8 wa1 = *reinterpret_cast<const bf16x8*>(w1s ? (w1D + (2 * kb + 1) * 256) : zb);
            f32x4 ab = MFMA16(wa1, XA,  zero4());
            f32x4 bb = MFMA16(wa1, XBv, zero4());
            H1A[kb] = mk_bfrag(pack2(sg(aa[0]), sg(aa[1])), pack2(sg(aa[2]), sg(aa[3])),
                               pack2(sg(ab[0]), sg(ab[1])), pack2(sg(ab[2]), sg(ab[3])));
            H1B[kb] = mk_bfrag(pack2(sg(ba[0]), sg(ba[1])), pack2(sg(ba[2]), sg(ba[3])),
                               pack2(sg(bb[0]), sg(bb[1])), pack2(sg(bb[2]), sg(bb[3])));
        }
        SCHED_FENCE();

        // ---- layer 2 + layer 3, pairwise: two out-tiles -> one L3 K-step ----
        // b2 bias enters as the accumulator initializer (no bias MFMA).
        f32x4 o3A = zero4(), o3B = zero4();
#pragma unroll
        for (int pt = 0; pt < 4; ++pt) {
            unsigned qa0, qa1, qa2, qa3, qb0, qb1, qb2, qb3;
            {
                const int ot = 2 * pt;
                f32x4 binit = *reinterpret_cast<const f32x4*>(b2D + ot * 16);
                f32x4 cA2 = binit, cB2 = binit;
#pragma unroll
                for (int kb = 0; kb < 4; ++kb) {
                    bf16x8 wa = *reinterpret_cast<const bf16x8*>(w2B + (ot * 4 + kb) * 512);
                    cA2 = MFMA16(wa, H1A[kb], cA2);
                    cB2 = MFMA16(wa, H1B[kb], cB2);
                }
                qa0 = pack2(sg(cA2[0]), sg(cA2[1]));
                qa1 = pack2(sg(cA2[2]), sg(cA2[3]));
                qb0 = pack2(sg(cB2[0]), sg(cB2[1]));
                qb1 = pack2(sg(cB2[2]), sg(cB2[3]));
            }
            {
                const int ot = 2 * pt + 1;
                f32x4 binit = *reinterpret_cast<const f32x4*>(b2D + ot * 16);
                f32x4 cA2 = binit, cB2 = binit;
#pragma unroll
                for (int kb = 0; kb < 4; ++kb) {
                    bf16x8 wa = *reinterpret_cast<const bf16x8*>(w2B + (ot * 4 + kb) * 512);
                    cA2 = MFMA16(wa, H1A[kb], cA2);
                    cB2 = MFMA16(wa, H1B[kb], cB2);
                }
                qa2 = pack2(sg(cA2[0]), sg(cA2[1]));
                qa3 = pack2(sg(cA2[2]), sg(cA2[3]));
                qb2 = pack2(sg(cB2[0]), sg(cB2[1]));
                qb3 = pack2(sg(cB2[2]), sg(cB2[3]));
            }
            bf16x8 w3a = *reinterpret_cast<const bf16x8*>(w3s ? (w3D + pt * 32) : zb);
            bf16x8 H2A = mk_bfrag(qa0, qa1, qa2, qa3);
            o3A = MFMA16(w3a, H2A, o3A);
            bf16x8 H2B = mk_bfrag(qb0, qb1, qb2, qb3);
            o3B = MFMA16(w3a, H2B, o3B);
            SCHED_FENCE();
        }

        if (q == 0) {   // output row 0 = quarter 0, reg 0; col = l15
            float vA = o3A[0] + b3v;
            float vB = o3B[0] + b3v;
            const int bbA = cA * 16 + l15;
            const int bbB = cB * 16 + l15;
            if (transposed) {
                dst[(size_t)e * BATCH + bbA] = vA;
                dst[(size_t)e * BATCH + bbB] = vB;
            } else {
                dst[(size_t)bbA * E_CNT + e] = vA;
                dst[(size_t)bbB * E_CNT + e] = vB;
            }
        }
    }
}

// wsT[e][b] (256 x 8192) -> out[b][e] (8192 x 256), 64x64 LDS tiles
__global__ __launch_bounds__(256)
void transpose_out_kernel(const float* __restrict__ wsT, float* __restrict__ out)
{
    __shared__ float tile[64][65];
    const int tx = threadIdx.x & 63;
    const int ty = threadIdx.x >> 6;
    const int b0 = blockIdx.x * 64;
    const int e0 = blockIdx.y * 64;
#pragma unroll
    for (int r = ty; r < 64; r += 4)
        tile[r][tx] = wsT[(size_t)(e0 + r) * BATCH + b0 + tx];
    __syncthreads();
#pragma unroll
    for (int r = ty; r < 64; r += 4)
        out[(size_t)(b0 + r) * E_CNT + e0 + tx] = tile[tx][r];
}

extern "C" void kernel_launch(void* const* d_in, const int* in_sizes, int n_in,
                              void* d_out, int out_size, void* d_ws, size_t ws_size,
                              hipStream_t stream) {
    const float* x  = (const float*)d_in[0];
    const float* W1 = (const float*)d_in[1];
    const float* b1 = (const float*)d_in[2];
    const float* W2 = (const float*)d_in[3];
    const float* b2 = (const float*)d_in[4];
    const float* W3 = (const float*)d_in[5];
    const float* b3 = (const float*)d_in[6];
    float* out = (float*)d_out;

    const size_t XBF_BYTES = (size_t)BATCH * 16 * sizeof(unsigned short);  // 256 KB
    const size_t WST_BYTES = (size_t)E_CNT * BATCH * sizeof(float);        // 8 MB

    const bool have_xbf = ws_size >= XBF_BYTES + WST_BYTES;
    const bool have_wst = ws_size >= WST_BYTES;

    unsigned short* xbf = (unsigned short*)d_ws;
    float* wsT = have_xbf ? (float*)((char*)d_ws + XBF_BYTES) : (float*)d_ws;

    if (have_xbf)
        prep_x_kernel<<<dim3((BATCH * 16 + 255) / 256), dim3(256), 0, stream>>>(x, xbf);

    if (have_wst) {
        mlp256_kernel<<<dim3(E_CNT * BPE), dim3(256), 0, stream>>>(
            x, xbf, W1, b1, W2, b2, W3, b3, wsT, have_xbf ? 1 : 0, 1);
        transpose_out_kernel<<<dim3(BATCH / 64, E_CNT / 64), dim3(256), 0, stream>>>(
            wsT, out);
    } else {
        mlp256_kernel<<<dim3(E_CNT * BPE), dim3(256), 0, stream>>>(
            x, xbf, W1, b1, W2, b2, W3, b3, out, 0, 0);
    }
}

// Round 16
// 161.894 us; speedup vs baseline: 1.1604x; 1.0012x over previous
//
#include <hip/hip_runtime.h>
#include <hip/hip_bf16.h>

// Problem geometry
#define E_CNT  256
#define D_IN   15
#define HDIM   128
#define BATCH  8192
#define NPAIR  256                  // 256 pairs of 16-row chunks per expert
#define BPE    3                    // blocks per expert -> grid 768; 512-thr blocks
#define NL2E   -1.44269504088896341f

typedef float f32x4 __attribute__((ext_vector_type(4)));
typedef short bf16x8 __attribute__((ext_vector_type(8)));
typedef unsigned int uint4v __attribute__((ext_vector_type(4)));

#define MFMA16(a, b, c) __builtin_amdgcn_mfma_f32_16x16x32_bf16((a), (b), (c), 0, 0, 0)
#define SCHED_FENCE() __builtin_amdgcn_sched_barrier(0)

// bf16 via round-half-up on the bit pattern (values finite here).
static __device__ inline unsigned short f2bf_rnd(float f) {
    unsigned u = __builtin_bit_cast(unsigned, f);
    return (unsigned short)((u + 0x8000u) >> 16);
}

// sigmoid with pre-scaled input az = -z*log2(e): s = rcp(1 + 2^az).
static __device__ inline float sg(float az) {
    float e = __builtin_amdgcn_exp2f(az);
    return __builtin_amdgcn_rcpf(1.0f + e);
}

// pack two floats to a bf16 pair (lo in low half), round-half-up: 3 VALU.
// (NOT hand-written v_cvt_pk_bf16_f32: that asm corrupted results in R2/R14.)
static __device__ inline unsigned pack2(float lo, float hi_) {
    unsigned a = __builtin_bit_cast(unsigned, lo) + 0x8000u;
    unsigned b = __builtin_bit_cast(unsigned, hi_) + 0x8000u;
#if __has_builtin(__builtin_amdgcn_perm)
    return __builtin_amdgcn_perm(b, a, 0x07060302u);   // D = {a.b2,a.b3,b.b2,b.b3}
#else
    return (a >> 16) | (b & 0xffff0000u);
#endif
}

// v_permlane32_swap_b32: a' = {a.g0,a.g1,b.g0,b.g1}, b' = {a.g2,a.g3,b.g2,b.g3}
static __device__ inline void pl32swap(unsigned &a, unsigned &b) {
#if __has_builtin(__builtin_amdgcn_permlane32_swap)
    auto r = __builtin_amdgcn_permlane32_swap(a, b, false, false);
    a = (unsigned)r[0];
    b = (unsigned)r[1];
#else
    asm volatile("v_permlane32_swap_b32 %0, %1" : "+v"(a), "+v"(b));
#endif
}

// v_permlane16_swap_b32: a' = {a.g0,b.g0,a.g2,b.g2}, b' = {a.g1,b.g1,a.g3,b.g3}
static __device__ inline void pl16swap(unsigned &a, unsigned &b) {
#if __has_builtin(__builtin_amdgcn_permlane16_swap)
    auto r = __builtin_amdgcn_permlane16_swap(a, b, false, false);
    a = (unsigned)r[0];
    b = (unsigned)r[1];
#else
    asm volatile("v_permlane16_swap_b32 %0, %1" : "+v"(a), "+v"(b));
#endif
}

static __device__ inline f32x4 zero4() { f32x4 z = {0.f, 0.f, 0.f, 0.f}; return z; }

// Redistribute two 16x16 C-tiles (pair-packed sigmoids) into one K=32 B-frag.
// (validated on-device R8-R15: absmax 0.0078)
static __device__ inline bf16x8 mk_bfrag(unsigned X0, unsigned X1, unsigned Y0, unsigned Y1) {
    pl32swap(X0, Y0);
    pl32swap(X1, Y1);
    pl16swap(X0, Y0);
    pl16swap(X1, Y1);
    uint4v u = {X0, X1, Y0, Y1};
    return __builtin_bit_cast(bf16x8, u);
}

// x[B][15] f32 -> xbf[B][16] bf16 with slot 15 = 1.0 (b1 partner)
__global__ __launch_bounds__(256)
void prep_x_kernel(const float* __restrict__ x, unsigned short* __restrict__ xbf)
{
    int i = blockIdx.x * 256 + threadIdx.x;
    if (i >= BATCH * 16) return;
    int row = i >> 4, k = i & 15;
    float v = (k < D_IN) ? x[row * D_IN + k] : 1.0f;
    xbf[i] = f2bf_rnd(v);
}

// 16x16x32 MFMA MLP, dual-chunk, fragment-ordered compressed LDS.
// R16 = R15 body (proven: VGPR 52 arch + ~24 acc = 76 demand) re-geared to
// 512-thread blocks at __launch_bounds__(512,6): cap 84 >= 76 demand (+8
// margin R13 lacked), 3 blocks/CU x 8 waves = 24 waves/CU = 6 waves/SIMD.
// LDS 37.9KB x 3 = 113.7KB <= 160KB.
__global__ __launch_bounds__(512, 6)
void mlp256_kernel(const float* __restrict__ x, const unsigned short* __restrict__ xbf,
                   const float* __restrict__ W1, const float* __restrict__ b1,
                   const float* __restrict__ W2, const float* __restrict__ b2,
                   const float* __restrict__ W3, const float* __restrict__ b3,
                   float* __restrict__ dst, int use_xbf, int transposed)
{
    __shared__ __align__(16) unsigned short w2f[32 * 512];   // 32 KB
    __shared__ __align__(16) unsigned short w1f[8 * 256];    // 4 KB (lanes<32)
    __shared__ __align__(16) float          b2l[128];        // 512 B (f32, scaled)
    __shared__ __align__(16) unsigned short w3f[128];        // 256 B (l15==0 lanes)
    __shared__ __align__(16) unsigned short zb[8];           // shared zero line

    const int tid  = threadIdx.x;
    const int wave = tid >> 6;          // 0..7
    const int lane = tid & 63;
    const int l15  = lane & 15;
    const int q    = lane >> 4;

    // grid = 768: e = bid&255, rg = bid>>8 (0..2). Blocks e, e+256, e+512 share
    // bid%8 -> same XCD under round-robin dispatch (W2 in one L2).
    const int bid = blockIdx.x;
    const int e   = bid & 255;
    const int rg  = bid >> 8;

    const float* w1p = W1 + e * (D_IN * HDIM);
    const float* b1p = b1 + e * HDIM;
    const float* w2p = W2 + e * (HDIM * HDIM);
    const float* b2p = b2 + e * HDIM;
    const float* w3p = W3 + e * HDIM;
    const float  b3v = b3[e];

    // ---- stage weights, fragment-ordered (prologue only; 512-thr strides) ----
    // W2: src (h,k) -> tile (h>>4)*4 + (k>>5), lane ((k>>3)&3)*16 + (h&15), j=k&7
    for (int i = tid; i < HDIM * HDIM; i += 512) {
        int h = i & 127, k = i >> 7;
        int t = ((h >> 4) << 2) + (k >> 5);
        int ln = (((k >> 3) & 3) << 4) + (h & 15);
        w2f[t * 512 + ln * 8 + (k & 7)] = f2bf_rnd(w2p[k * HDIM + h] * NL2E);
    }
    // W1 (+b1): 8 tiles x 32 lanes x 8; k = (ln>>4)*8 + j in 0..15
    for (int i = tid; i < 8 * 256; i += 512) {
        int t = i >> 8, ln = (i >> 3) & 31, j = i & 7;
        int k = (ln >> 4) * 8 + j, h = t * 16 + (ln & 15);
        float v = (k < D_IN) ? w1p[k * HDIM + h] : b1p[h];
        w1f[i] = f2bf_rnd(v * NL2E);
    }
    // b2 as f32 (scaled): accumulator C-init; w3: [kb][q][8] unscaled; zero line
    if (tid < 128) b2l[tid] = b2p[tid] * NL2E;
    if (tid < 128) w3f[tid] = f2bf_rnd(w3p[tid]);
    if (tid < 8)   zb[tid] = 0;

    __syncthreads();   // weights staged; waves independent from here

    // per-lane bases + selects (quarter-uniform; compile to v_cndmask on addr)
    const bool w1s = (lane < 32);
    const bool w3s = (l15 == 0);
    const unsigned short* w1D = w1f + lane * 8;        // + t*256
    const unsigned short* w2B = w2f + lane * 8;        // + tile*512
    const float*          b2D = b2l + q * 4;           // + ot*16 (l15-independent)
    const unsigned short* w3D = w3f + q * 8;           // + kb*32
    const int xoff = l15 * 16 + (q & 1) * 8;

    // pairs: slot = rg + 3*wave (0..23 bijective); p = slot + 24*j
    for (int p = rg + 3 * wave; p < NPAIR; p += 24) {
        const int cA = 2 * p, cB = 2 * p + 1;

        bf16x8 XA, XBv;
        if (use_xbf) {
            XA  = *reinterpret_cast<const bf16x8*>(xbf + (size_t)cA * 256 + xoff);
            XBv = *reinterpret_cast<const bf16x8*>(xbf + (size_t)cB * 256 + xoff);
        } else {
            const float* xa = x + (size_t)(cA * 16 + l15) * D_IN;
            const float* xb = x + (size_t)(cB * 16 + l15) * D_IN;
#pragma unroll
            for (int j = 0; j < 8; ++j) {
                int k = (q & 1) * 8 + j;
                XA[j]  = (short)f2bf_rnd((k < D_IN) ? xa[k] : 1.0f);
                XBv[j] = (short)f2bf_rnd((k < D_IN) ? xb[k] : 1.0f);
            }
        }

        // ---- layer 1, pairwise: two h-tiles -> one K=32 B-frag, both chunks ----
        bf16x8 H1A[4], H1B[4];
#pragma unroll
        for (int kb = 0; kb < 4; ++kb) {
            bf16x8 wa0 = *reinterpret_cast<const bf16x8*>(w1s ? (w1D + (2 * kb) * 256) : zb);
            f32x4 aa = MFMA16(wa0, XA,  zero4());
            f32x4 ba = MFMA16(wa0, XBv, zero4());
            bf16x8 wa1 = *reinterpret_cast<const bf16x8*>(w1s ? (w1D + (2 * kb + 1) * 256) : zb);
            f32x4 ab = MFMA16(wa1, XA,  zero4());
            f32x4 bb = MFMA16(wa1, XBv, zero4());
            H1A[kb] = mk_bfrag(pack2(sg(aa[0]), sg(aa[1])), pack2(sg(aa[2]), sg(aa[3])),
                               pack2(sg(ab[0]), sg(ab[1])), pack2(sg(ab[2]), sg(ab[3])));
            H1B[kb] = mk_bfrag(pack2(sg(ba[0]), sg(ba[1])), pack2(sg(ba[2]), sg(ba[3])),
                               pack2(sg(bb[0]), sg(bb[1])), pack2(sg(bb[2]), sg(bb[3])));
        }
        SCHED_FENCE();

        // ---- layer 2 + layer 3, pairwise: two out-tiles -> one L3 K-step ----
        // b2 bias enters as the accumulator initializer (no bias MFMA).
        f32x4 o3A = zero4(), o3B = zero4();
#pragma unroll
        for (int pt = 0; pt < 4; ++pt) {
            unsigned qa0, qa1, qa2, qa3, qb0, qb1, qb2, qb3;
            {
                const int ot = 2 * pt;
                f32x4 binit = *reinterpret_cast<const f32x4*>(b2D + ot * 16);
                f32x4 cA2 = binit, cB2 = binit;
#pragma unroll
                for (int kb = 0; kb < 4; ++kb) {
                    bf16x8 wa = *reinterpret_cast<const bf16x8*>(w2B + (ot * 4 + kb) * 512);
                    cA2 = MFMA16(wa, H1A[kb], cA2);
                    cB2 = MFMA16(wa, H1B[kb], cB2);
                }
                qa0 = pack2(sg(cA2[0]), sg(cA2[1]));
                qa1 = pack2(sg(cA2[2]), sg(cA2[3]));
                qb0 = pack2(sg(cB2[0]), sg(cB2[1]));
                qb1 = pack2(sg(cB2[2]), sg(cB2[3]));
            }
            {
                const int ot = 2 * pt + 1;
                f32x4 binit = *reinterpret_cast<const f32x4*>(b2D + ot * 16);
                f32x4 cA2 = binit, cB2 = binit;
#pragma unroll
                for (int kb = 0; kb < 4; ++kb) {
                    bf16x8 wa = *reinterpret_cast<const bf16x8*>(w2B + (ot * 4 + kb) * 512);
                    cA2 = MFMA16(wa, H1A[kb], cA2);
                    cB2 = MFMA16(wa, H1B[kb], cB2);
                }
                qa2 = pack2(sg(cA2[0]), sg(cA2[1]));
                qa3 = pack2(sg(cA2[2]), sg(cA2[3]));
                qb2 = pack2(sg(cB2[0]), sg(cB2[1]));
                qb3 = pack2(sg(cB2[2]), sg(cB2[3]));
            }
            bf16x8 w3a = *reinterpret_cast<const bf16x8*>(w3s ? (w3D + pt * 32) : zb);
            bf16x8 H2A = mk_bfrag(qa0, qa1, qa2, qa3);
            o3A = MFMA16(w3a, H2A, o3A);
            bf16x8 H2B = mk_bfrag(qb0, qb1, qb2, qb3);
            o3B = MFMA16(w3a, H2B, o3B);
            SCHED_FENCE();
        }

        if (q == 0) {   // output row 0 = quarter 0, reg 0; col = l15
            float vA = o3A[0] + b3v;
            float vB = o3B[0] + b3v;
            const int bbA = cA * 16 + l15;
            const int bbB = cB * 16 + l15;
            if (transposed) {
                dst[(size_t)e * BATCH + bbA] = vA;
                dst[(size_t)e * BATCH + bbB] = vB;
            } else {
                dst[(size_t)bbA * E_CNT + e] = vA;
                dst[(size_t)bbB * E_CNT + e] = vB;
            }
        }
    }
}

// wsT[e][b] (256 x 8192) -> out[b][e] (8192 x 256), 64x64 LDS tiles
__global__ __launch_bounds__(256)
void transpose_out_kernel(const float* __restrict__ wsT, float* __restrict__ out)
{
    __shared__ float tile[64][65];
    const int tx = threadIdx.x & 63;
    const int ty = threadIdx.x >> 6;
    const int b0 = blockIdx.x * 64;
    const int e0 = blockIdx.y * 64;
#pragma unroll
    for (int r = ty; r < 64; r += 4)
        tile[r][tx] = wsT[(size_t)(e0 + r) * BATCH + b0 + tx];
    __syncthreads();
#pragma unroll
    for (int r = ty; r < 64; r += 4)
        out[(size_t)(b0 + r) * E_CNT + e0 + tx] = tile[tx][r];
}

extern "C" void kernel_launch(void* const* d_in, const int* in_sizes, int n_in,
                              void* d_out, int out_size, void* d_ws, size_t ws_size,
                              hipStream_t stream) {
    const float* x  = (const float*)d_in[0];
    const float* W1 = (const float*)d_in[1];
    const float* b1 = (const float*)d_in[2];
    const float* W2 = (const float*)d_in[3];
    const float* b2 = (const float*)d_in[4];
    const float* W3 = (const float*)d_in[5];
    const float* b3 = (const float*)d_in[6];
    float* out = (float*)d_out;

    const size_t XBF_BYTES = (size_t)BATCH * 16 * sizeof(unsigned short);  // 256 KB
    const size_t WST_BYTES = (size_t)E_CNT * BATCH * sizeof(float);        // 8 MB

    const bool have_xbf = ws_size >= XBF_BYTES + WST_BYTES;
    const bool have_wst = ws_size >= WST_BYTES;

    unsigned short* xbf = (unsigned short*)d_ws;
    float* wsT = have_xbf ? (float*)((char*)d_ws + XBF_BYTES) : (float*)d_ws;

    if (have_xbf)
        prep_x_kernel<<<dim3((BATCH * 16 + 255) / 256), dim3(256), 0, stream>>>(x, xbf);

    if (have_wst) {
        mlp256_kernel<<<dim3(E_CNT * BPE), dim3(512), 0, stream>>>(
            x, xbf, W1, b1, W2, b2, W3, b3, wsT, have_xbf ? 1 : 0, 1);
        transpose_out_kernel<<<dim3(BATCH / 64, E_CNT / 64), dim3(256), 0, stream>>>(
            wsT, out);
    } else {
        mlp256_kernel<<<dim3(E_CNT * BPE), dim3(512), 0, stream>>>(
            x, xbf, W1, b1, W2, b2, W3, b3, out, 0, 0);
    }
}

// Round 17
// 149.315 us; speedup vs baseline: 1.2581x; 1.0842x over previous
//
#include <hip/hip_runtime.h>
#include <hip/hip_bf16.h>

// Problem geometry
#define E_CNT  256
#define D_IN   15
#define HDIM   128
#define BATCH  8192
#define NPAIR  256                  // 256 pairs of 16-row chunks per expert
#define BPE    4                    // blocks per expert -> grid 1024, 4 blocks/CU
#define NL2E   -1.44269504088896341f

typedef float f32x4 __attribute__((ext_vector_type(4)));
typedef short bf16x8 __attribute__((ext_vector_type(8)));
typedef unsigned int uint4v __attribute__((ext_vector_type(4)));

#define MFMA16(a, b, c) __builtin_amdgcn_mfma_f32_16x16x32_bf16((a), (b), (c), 0, 0, 0)
#define SCHED_FENCE() __builtin_amdgcn_sched_barrier(0)

// bf16 via round-half-up on the bit pattern (values finite here).
static __device__ inline unsigned short f2bf_rnd(float f) {
    unsigned u = __builtin_bit_cast(unsigned, f);
    return (unsigned short)((u + 0x8000u) >> 16);
}

// sigmoid with pre-scaled input az = -z*log2(e): s = rcp(1 + 2^az).
static __device__ inline float sg(float az) {
    float e = __builtin_amdgcn_exp2f(az);
    return __builtin_amdgcn_rcpf(1.0f + e);
}

// pack two floats to a bf16 pair (lo in low half), round-half-up: 3 VALU.
// (NOT hand-written v_cvt_pk_bf16_f32: that asm corrupted results in R2/R14.)
static __device__ inline unsigned pack2(float lo, float hi_) {
    unsigned a = __builtin_bit_cast(unsigned, lo) + 0x8000u;
    unsigned b = __builtin_bit_cast(unsigned, hi_) + 0x8000u;
#if __has_builtin(__builtin_amdgcn_perm)
    return __builtin_amdgcn_perm(b, a, 0x07060302u);   // D = {a.b2,a.b3,b.b2,b.b3}
#else
    return (a >> 16) | (b & 0xffff0000u);
#endif
}

// v_permlane32_swap_b32: a' = {a.g0,a.g1,b.g0,b.g1}, b' = {a.g2,a.g3,b.g2,b.g3}
static __device__ inline void pl32swap(unsigned &a, unsigned &b) {
#if __has_builtin(__builtin_amdgcn_permlane32_swap)
    auto r = __builtin_amdgcn_permlane32_swap(a, b, false, false);
    a = (unsigned)r[0];
    b = (unsigned)r[1];
#else
    asm volatile("v_permlane32_swap_b32 %0, %1" : "+v"(a), "+v"(b));
#endif
}

// v_permlane16_swap_b32: a' = {a.g0,b.g0,a.g2,b.g2}, b' = {a.g1,b.g1,a.g3,b.g3}
static __device__ inline void pl16swap(unsigned &a, unsigned &b) {
#if __has_builtin(__builtin_amdgcn_permlane16_swap)
    auto r = __builtin_amdgcn_permlane16_swap(a, b, false, false);
    a = (unsigned)r[0];
    b = (unsigned)r[1];
#else
    asm volatile("v_permlane16_swap_b32 %0, %1" : "+v"(a), "+v"(b));
#endif
}

static __device__ inline f32x4 zero4() { f32x4 z = {0.f, 0.f, 0.f, 0.f}; return z; }

// Redistribute two 16x16 C-tiles (pair-packed sigmoids) into one K=32 B-frag.
// (validated on-device R8-R16: absmax 0.0078)
static __device__ inline bf16x8 mk_bfrag(unsigned X0, unsigned X1, unsigned Y0, unsigned Y1) {
    pl32swap(X0, Y0);
    pl32swap(X1, Y1);
    pl16swap(X0, Y0);
    pl16swap(X1, Y1);
    uint4v u = {X0, X1, Y0, Y1};
    return __builtin_bit_cast(bf16x8, u);
}

// x[B][15] f32 -> xbf[B][16] bf16 with slot 15 = 1.0 (b1 partner)
__global__ __launch_bounds__(256)
void prep_x_kernel(const float* __restrict__ x, unsigned short* __restrict__ xbf)
{
    int i = blockIdx.x * 256 + threadIdx.x;
    if (i >= BATCH * 16) return;
    int row = i >> 4, k = i & 15;
    float v = (k < D_IN) ? x[row * D_IN + k] : 1.0f;
    xbf[i] = f2bf_rnd(v);
}

// 16x16x32 MFMA MLP, dual-chunk, fragment-ordered compressed LDS (R15
// geometry: 256 thr, (256,4), 4 waves/SIMD, no spill).
// R17 delta: LAYER 3 IS A VALU DOT, not an MFMA. Lane (q,l15) reg r of the
// L2 C-tile holds h2[ot*16+q*4+r][col l15] (C/D map, validated R8+), so
// o += sg(c2[r]) * w3[ot*16+q*4+r] with a final cross-q shuffle reduce
// replaces per-pair: 32 pack2 + 8 mk_bfrag + 8 MFMAs. h2 enters L3 at f32.
__global__ __launch_bounds__(256, 4)
void mlp256_kernel(const float* __restrict__ x, const unsigned short* __restrict__ xbf,
                   const float* __restrict__ W1, const float* __restrict__ b1,
                   const float* __restrict__ W2, const float* __restrict__ b2,
                   const float* __restrict__ W3, const float* __restrict__ b3,
                   float* __restrict__ dst, int use_xbf, int transposed)
{
    __shared__ __align__(16) unsigned short w2f[32 * 512];   // 32 KB
    __shared__ __align__(16) unsigned short w1f[8 * 256];    // 4 KB (lanes<32)
    __shared__ __align__(16) float          b2l[128];        // 512 B (f32, scaled)
    __shared__ __align__(16) float          w3l[128];        // 512 B (f32, natural order)
    __shared__ __align__(16) unsigned short zb[8];           // shared zero line

    const int tid  = threadIdx.x;
    const int wave = tid >> 6;
    const int lane = tid & 63;
    const int l15  = lane & 15;
    const int q    = lane >> 4;

    // grid = 1024: e = bid&255, rg = bid>>8 (0..3). Blocks e,e+256,e+512,e+768
    // share bid%8 -> same XCD under round-robin dispatch (W2 in one L2).
    const int bid = blockIdx.x;
    const int e   = bid & 255;
    const int rg  = bid >> 8;

    const float* w1p = W1 + e * (D_IN * HDIM);
    const float* b1p = b1 + e * HDIM;
    const float* w2p = W2 + e * (HDIM * HDIM);
    const float* b2p = b2 + e * HDIM;
    const float* w3p = W3 + e * HDIM;
    const float  b3v = b3[e];

    // ---- stage weights, fragment-ordered (prologue only) ----
    // W2: src (h,k) -> tile (h>>4)*4 + (k>>5), lane ((k>>3)&3)*16 + (h&15), j=k&7
    for (int i = tid; i < HDIM * HDIM; i += 256) {
        int h = i & 127, k = i >> 7;
        int t = ((h >> 4) << 2) + (k >> 5);
        int ln = (((k >> 3) & 3) << 4) + (h & 15);
        w2f[t * 512 + ln * 8 + (k & 7)] = f2bf_rnd(w2p[k * HDIM + h] * NL2E);
    }
    // W1 (+b1): 8 tiles x 32 lanes x 8; k = (ln>>4)*8 + j in 0..15
    for (int i = tid; i < 8 * 256; i += 256) {
        int t = i >> 8, ln = (i >> 3) & 31, j = i & 7;
        int k = (ln >> 4) * 8 + j, h = t * 16 + (ln & 15);
        float v = (k < D_IN) ? w1p[k * HDIM + h] : b1p[h];
        w1f[i] = f2bf_rnd(v * NL2E);
    }
    // b2 (scaled) as accumulator C-init; w3 f32 natural; zero line
    if (tid < 128) b2l[tid] = b2p[tid] * NL2E;
    if (tid < 128) w3l[tid] = w3p[tid];
    if (tid < 8)   zb[tid] = 0;

    __syncthreads();   // weights staged; waves independent from here

    // per-lane bases + selects (quarter-uniform; compile to v_cndmask on addr)
    const bool w1s = (lane < 32);
    const unsigned short* w1D = w1f + lane * 8;        // + t*256
    const unsigned short* w2B = w2f + lane * 8;        // + tile*512
    const float*          b2D = b2l + q * 4;           // + ot*16 (l15-independent)
    const float*          w3V = w3l + q * 4;           // + ot*16 (l15-independent)
    const int xoff = l15 * 16 + (q & 1) * 8;

    // pairs: slot = rg + 4*wave (0..15); p = slot + 16*j, 16 pairs per wave
    for (int p = rg + 4 * wave; p < NPAIR; p += 16) {
        const int cA = 2 * p, cB = 2 * p + 1;

        bf16x8 XA, XBv;
        if (use_xbf) {
            XA  = *reinterpret_cast<const bf16x8*>(xbf + (size_t)cA * 256 + xoff);
            XBv = *reinterpret_cast<const bf16x8*>(xbf + (size_t)cB * 256 + xoff);
        } else {
            const float* xa = x + (size_t)(cA * 16 + l15) * D_IN;
            const float* xb = x + (size_t)(cB * 16 + l15) * D_IN;
#pragma unroll
            for (int j = 0; j < 8; ++j) {
                int k = (q & 1) * 8 + j;
                XA[j]  = (short)f2bf_rnd((k < D_IN) ? xa[k] : 1.0f);
                XBv[j] = (short)f2bf_rnd((k < D_IN) ? xb[k] : 1.0f);
            }
        }

        // ---- layer 1, pairwise: two h-tiles -> one K=32 B-frag, both chunks ----
        bf16x8 H1A[4], H1B[4];
#pragma unroll
        for (int kb = 0; kb < 4; ++kb) {
            bf16x8 wa0 = *reinterpret_cast<const bf16x8*>(w1s ? (w1D + (2 * kb) * 256) : zb);
            f32x4 aa = MFMA16(wa0, XA,  zero4());
            f32x4 ba = MFMA16(wa0, XBv, zero4());
            bf16x8 wa1 = *reinterpret_cast<const bf16x8*>(w1s ? (w1D + (2 * kb + 1) * 256) : zb);
            f32x4 ab = MFMA16(wa1, XA,  zero4());
            f32x4 bb = MFMA16(wa1, XBv, zero4());
            H1A[kb] = mk_bfrag(pack2(sg(aa[0]), sg(aa[1])), pack2(sg(aa[2]), sg(aa[3])),
                               pack2(sg(ab[0]), sg(ab[1])), pack2(sg(ab[2]), sg(ab[3])));
            H1B[kb] = mk_bfrag(pack2(sg(ba[0]), sg(ba[1])), pack2(sg(ba[2]), sg(ba[3])),
                               pack2(sg(bb[0]), sg(bb[1])), pack2(sg(bb[2]), sg(bb[3])));
        }
        SCHED_FENCE();

        // ---- layer 2 (MFMA, b2 as C-init) + layer 3 (VALU dot) ----
        float oA = 0.0f, oB = 0.0f;
#pragma unroll
        for (int ot = 0; ot < 8; ++ot) {
            f32x4 binit = *reinterpret_cast<const f32x4*>(b2D + ot * 16);
            f32x4 cA2 = binit, cB2 = binit;
#pragma unroll
            for (int kb = 0; kb < 4; ++kb) {
                bf16x8 wa = *reinterpret_cast<const bf16x8*>(w2B + (ot * 4 + kb) * 512);
                cA2 = MFMA16(wa, H1A[kb], cA2);
                cB2 = MFMA16(wa, H1B[kb], cB2);
            }
            // lane (q,l15) reg r holds pre-act of h = ot*16 + q*4 + r, col l15
            f32x4 w3v = *reinterpret_cast<const f32x4*>(w3V + ot * 16);
#pragma unroll
            for (int r = 0; r < 4; ++r) {
                oA += sg(cA2[r]) * w3v[r];
                oB += sg(cB2[r]) * w3v[r];
            }
            if (ot & 1) SCHED_FENCE();
        }

        // cross-q reduce (cols split over 4 quarter-groups)
        oA += __shfl_xor(oA, 16);
        oA += __shfl_xor(oA, 32);
        oB += __shfl_xor(oB, 16);
        oB += __shfl_xor(oB, 32);

        if (q == 0) {   // col = l15
            float vA = oA + b3v;
            float vB = oB + b3v;
            const int bbA = cA * 16 + l15;
            const int bbB = cB * 16 + l15;
            if (transposed) {
                dst[(size_t)e * BATCH + bbA] = vA;
                dst[(size_t)e * BATCH + bbB] = vB;
            } else {
                dst[(size_t)bbA * E_CNT + e] = vA;
                dst[(size_t)bbB * E_CNT + e] = vB;
            }
        }
    }
}

// wsT[e][b] (256 x 8192) -> out[b][e] (8192 x 256), 64x64 LDS tiles
__global__ __launch_bounds__(256)
void transpose_out_kernel(const float* __restrict__ wsT, float* __restrict__ out)
{
    __shared__ float tile[64][65];
    const int tx = threadIdx.x & 63;
    const int ty = threadIdx.x >> 6;
    const int b0 = blockIdx.x * 64;
    const int e0 = blockIdx.y * 64;
#pragma unroll
    for (int r = ty; r < 64; r += 4)
        tile[r][tx] = wsT[(size_t)(e0 + r) * BATCH + b0 + tx];
    __syncthreads();
#pragma unroll
    for (int r = ty; r < 64; r += 4)
        out[(size_t)(b0 + r) * E_CNT + e0 + tx] = tile[tx][r];
}

extern "C" void kernel_launch(void* const* d_in, const int* in_sizes, int n_in,
                              void* d_out, int out_size, void* d_ws, size_t ws_size,
                              hipStream_t stream) {
    const float* x  = (const float*)d_in[0];
    const float* W1 = (const float*)d_in[1];
    const float* b1 = (const float*)d_in[2];
    const float* W2 = (const float*)d_in[3];
    const float* b2 = (const float*)d_in[4];
    const float* W3 = (const float*)d_in[5];
    const float* b3 = (const float*)d_in[6];
    float* out = (float*)d_out;

    const size_t XBF_BYTES = (size_t)BATCH * 16 * sizeof(unsigned short);  // 256 KB
    const size_t WST_BYTES = (size_t)E_CNT * BATCH * sizeof(float);        // 8 MB

    const bool have_xbf = ws_size >= XBF_BYTES + WST_BYTES;
    const bool have_wst = ws_size >= WST_BYTES;

    unsigned short* xbf = (unsigned short*)d_ws;
    float* wsT = have_xbf ? (float*)((char*)d_ws + XBF_BYTES) : (float*)d_ws;

    if (have_xbf)
        prep_x_kernel<<<dim3((BATCH * 16 + 255) / 256), dim3(256), 0, stream>>>(x, xbf);

    if (have_wst) {
        mlp256_kernel<<<dim3(E_CNT * BPE), dim3(256), 0, stream>>>(
            x, xbf, W1, b1, W2, b2, W3, b3, wsT, have_xbf ? 1 : 0, 1);
        transpose_out_kernel<<<dim3(BATCH / 64, E_CNT / 64), dim3(256), 0, stream>>>(
            wsT, out);
    } else {
        mlp256_kernel<<<dim3(E_CNT * BPE), dim3(256), 0, stream>>>(
            x, xbf, W1, b1, W2, b2, W3, b3, out, 0, 0);
    }
}

// Round 18
// 142.252 us; speedup vs baseline: 1.3206x; 1.0497x over previous
//
#include <hip/hip_runtime.h>
#include <hip/hip_bf16.h>

// Problem geometry
#define E_CNT  256
#define D_IN   15
#define HDIM   128
#define BATCH  8192
#define NPAIR  256                  // 256 pairs of 16-row chunks per expert
#define BPE    4                    // blocks per expert -> grid 1024, 4 blocks/CU
#define NL2E   -1.44269504088896341f

typedef float f32x4 __attribute__((ext_vector_type(4)));
typedef short bf16x8 __attribute__((ext_vector_type(8)));
typedef unsigned int uint4v __attribute__((ext_vector_type(4)));

#define MFMA16(a, b, c) __builtin_amdgcn_mfma_f32_16x16x32_bf16((a), (b), (c), 0, 0, 0)
#define SCHED_FENCE() __builtin_amdgcn_sched_barrier(0)

// bf16 via round-half-up on the bit pattern (values finite here).
static __device__ inline unsigned short f2bf_rnd(float f) {
    unsigned u = __builtin_bit_cast(unsigned, f);
    return (unsigned short)((u + 0x8000u) >> 16);
}

// sigmoid with pre-scaled input az = -z*log2(e): s = rcp(1 + 2^az).
static __device__ inline float sg(float az) {
    float e = __builtin_amdgcn_exp2f(az);
    return __builtin_amdgcn_rcpf(1.0f + e);
}

// pack two sigmoid outputs ([0,1]) to a bf16 pair by TRUNCATION: 1 op.
// (<=1 ulp negative bias per element; random-sign w2 cancels it in the L2 sum.
//  NOT hand-written v_cvt_pk_bf16_f32: that asm corrupted results in R2/R14.)
static __device__ inline unsigned pack2t(float lo, float hi_) {
    unsigned a = __builtin_bit_cast(unsigned, lo);
    unsigned b = __builtin_bit_cast(unsigned, hi_);
#if __has_builtin(__builtin_amdgcn_perm)
    return __builtin_amdgcn_perm(b, a, 0x07060302u);   // D = {a.b2,a.b3,b.b2,b.b3}
#else
    return (a >> 16) | (b & 0xffff0000u);
#endif
}

// v_permlane32_swap_b32: a' = {a.g0,a.g1,b.g0,b.g1}, b' = {a.g2,a.g3,b.g2,b.g3}
static __device__ inline void pl32swap(unsigned &a, unsigned &b) {
#if __has_builtin(__builtin_amdgcn_permlane32_swap)
    auto r = __builtin_amdgcn_permlane32_swap(a, b, false, false);
    a = (unsigned)r[0];
    b = (unsigned)r[1];
#else
    asm volatile("v_permlane32_swap_b32 %0, %1" : "+v"(a), "+v"(b));
#endif
}

// v_permlane16_swap_b32: a' = {a.g0,b.g0,a.g2,b.g2}, b' = {a.g1,b.g1,a.g3,b.g3}
static __device__ inline void pl16swap(unsigned &a, unsigned &b) {
#if __has_builtin(__builtin_amdgcn_permlane16_swap)
    auto r = __builtin_amdgcn_permlane16_swap(a, b, false, false);
    a = (unsigned)r[0];
    b = (unsigned)r[1];
#else
    asm volatile("v_permlane16_swap_b32 %0, %1" : "+v"(a), "+v"(b));
#endif
}

static __device__ inline f32x4 zero4() { f32x4 z = {0.f, 0.f, 0.f, 0.f}; return z; }

// Redistribute two 16x16 C-tiles (pair-packed sigmoids) into one K=32 B-frag.
// (validated on-device R8-R17: absmax 0.0078)
static __device__ inline bf16x8 mk_bfrag(unsigned X0, unsigned X1, unsigned Y0, unsigned Y1) {
    pl32swap(X0, Y0);
    pl32swap(X1, Y1);
    pl16swap(X0, Y0);
    pl16swap(X1, Y1);
    uint4v u = {X0, X1, Y0, Y1};
    return __builtin_bit_cast(bf16x8, u);
}

// x[B][15] f32 -> xbf[B][16] bf16 with slot 15 = 1.0 (b1 partner)
__global__ __launch_bounds__(256)
void prep_x_kernel(const float* __restrict__ x, unsigned short* __restrict__ xbf)
{
    int i = blockIdx.x * 256 + threadIdx.x;
    if (i >= BATCH * 16) return;
    int row = i >> 4, k = i & 15;
    float v = (k < D_IN) ? x[row * D_IN + k] : 1.0f;
    xbf[i] = f2bf_rnd(v);
}

// 16x16x32 MFMA MLP, dual-chunk, fragment-ordered compressed LDS (R15/R17
// geometry: 256 thr, (256,4), 4 waves/SIMD, no spill).
// R18 deltas: (1) L1 pack by truncation (pack2t: 1 op, was 3) — saves 64
// VALU/pair; (2) L2-loop fences removed (kept post-L1) so the scheduler
// hoists next ot-tile's 4 ds_read_b128 under the current sigmoid/dot chain
// (bounded +16 regs; 76-reg margin available).
__global__ __launch_bounds__(256, 4)
void mlp256_kernel(const float* __restrict__ x, const unsigned short* __restrict__ xbf,
                   const float* __restrict__ W1, const float* __restrict__ b1,
                   const float* __restrict__ W2, const float* __restrict__ b2,
                   const float* __restrict__ W3, const float* __restrict__ b3,
                   float* __restrict__ dst, int use_xbf, int transposed)
{
    __shared__ __align__(16) unsigned short w2f[32 * 512];   // 32 KB
    __shared__ __align__(16) unsigned short w1f[8 * 256];    // 4 KB (lanes<32)
    __shared__ __align__(16) float          b2l[128];        // 512 B (f32, scaled)
    __shared__ __align__(16) float          w3l[128];        // 512 B (f32, natural order)
    __shared__ __align__(16) unsigned short zb[8];           // shared zero line

    const int tid  = threadIdx.x;
    const int wave = tid >> 6;
    const int lane = tid & 63;
    const int l15  = lane & 15;
    const int q    = lane >> 4;

    // grid = 1024: e = bid&255, rg = bid>>8 (0..3). Blocks e,e+256,e+512,e+768
    // share bid%8 -> same XCD under round-robin dispatch (W2 in one L2).
    const int bid = blockIdx.x;
    const int e   = bid & 255;
    const int rg  = bid >> 8;

    const float* w1p = W1 + e * (D_IN * HDIM);
    const float* b1p = b1 + e * HDIM;
    const float* w2p = W2 + e * (HDIM * HDIM);
    const float* b2p = b2 + e * HDIM;
    const float* w3p = W3 + e * HDIM;
    const float  b3v = b3[e];

    // ---- stage weights, fragment-ordered (prologue only) ----
    // W2: src (h,k) -> tile (h>>4)*4 + (k>>5), lane ((k>>3)&3)*16 + (h&15), j=k&7
    for (int i = tid; i < HDIM * HDIM; i += 256) {
        int h = i & 127, k = i >> 7;
        int t = ((h >> 4) << 2) + (k >> 5);
        int ln = (((k >> 3) & 3) << 4) + (h & 15);
        w2f[t * 512 + ln * 8 + (k & 7)] = f2bf_rnd(w2p[k * HDIM + h] * NL2E);
    }
    // W1 (+b1): 8 tiles x 32 lanes x 8; k = (ln>>4)*8 + j in 0..15
    for (int i = tid; i < 8 * 256; i += 256) {
        int t = i >> 8, ln = (i >> 3) & 31, j = i & 7;
        int k = (ln >> 4) * 8 + j, h = t * 16 + (ln & 15);
        float v = (k < D_IN) ? w1p[k * HDIM + h] : b1p[h];
        w1f[i] = f2bf_rnd(v * NL2E);
    }
    // b2 (scaled) as accumulator C-init; w3 f32 natural; zero line
    if (tid < 128) b2l[tid] = b2p[tid] * NL2E;
    if (tid < 128) w3l[tid] = w3p[tid];
    if (tid < 8)   zb[tid] = 0;

    __syncthreads();   // weights staged; waves independent from here

    // per-lane bases + selects (quarter-uniform; compile to v_cndmask on addr)
    const bool w1s = (lane < 32);
    const unsigned short* w1D = w1f + lane * 8;        // + t*256
    const unsigned short* w2B = w2f + lane * 8;        // + tile*512
    const float*          b2D = b2l + q * 4;           // + ot*16 (l15-independent)
    const float*          w3V = w3l + q * 4;           // + ot*16 (l15-independent)
    const int xoff = l15 * 16 + (q & 1) * 8;

    // pairs: slot = rg + 4*wave (0..15); p = slot + 16*j, 16 pairs per wave
    for (int p = rg + 4 * wave; p < NPAIR; p += 16) {
        const int cA = 2 * p, cB = 2 * p + 1;

        bf16x8 XA, XBv;
        if (use_xbf) {
            XA  = *reinterpret_cast<const bf16x8*>(xbf + (size_t)cA * 256 + xoff);
            XBv = *reinterpret_cast<const bf16x8*>(xbf + (size_t)cB * 256 + xoff);
        } else {
            const float* xa = x + (size_t)(cA * 16 + l15) * D_IN;
            const float* xb = x + (size_t)(cB * 16 + l15) * D_IN;
#pragma unroll
            for (int j = 0; j < 8; ++j) {
                int k = (q & 1) * 8 + j;
                XA[j]  = (short)f2bf_rnd((k < D_IN) ? xa[k] : 1.0f);
                XBv[j] = (short)f2bf_rnd((k < D_IN) ? xb[k] : 1.0f);
            }
        }

        // ---- layer 1, pairwise: two h-tiles -> one K=32 B-frag, both chunks ----
        bf16x8 H1A[4], H1B[4];
#pragma unroll
        for (int kb = 0; kb < 4; ++kb) {
            bf16x8 wa0 = *reinterpret_cast<const bf16x8*>(w1s ? (w1D + (2 * kb) * 256) : zb);
            f32x4 aa = MFMA16(wa0, XA,  zero4());
            f32x4 ba = MFMA16(wa0, XBv, zero4());
            bf16x8 wa1 = *reinterpret_cast<const bf16x8*>(w1s ? (w1D + (2 * kb + 1) * 256) : zb);
            f32x4 ab = MFMA16(wa1, XA,  zero4());
            f32x4 bb = MFMA16(wa1, XBv, zero4());
            H1A[kb] = mk_bfrag(pack2t(sg(aa[0]), sg(aa[1])), pack2t(sg(aa[2]), sg(aa[3])),
                               pack2t(sg(ab[0]), sg(ab[1])), pack2t(sg(ab[2]), sg(ab[3])));
            H1B[kb] = mk_bfrag(pack2t(sg(ba[0]), sg(ba[1])), pack2t(sg(ba[2]), sg(ba[3])),
                               pack2t(sg(bb[0]), sg(bb[1])), pack2t(sg(bb[2]), sg(bb[3])));
        }
        SCHED_FENCE();

        // ---- layer 2 (MFMA, b2 as C-init) + layer 3 (VALU dot) ----
        float oA = 0.0f, oB = 0.0f;
#pragma unroll
        for (int ot = 0; ot < 8; ++ot) {
            f32x4 binit = *reinterpret_cast<const f32x4*>(b2D + ot * 16);
            f32x4 cA2 = binit, cB2 = binit;
#pragma unroll
            for (int kb = 0; kb < 4; ++kb) {
                bf16x8 wa = *reinterpret_cast<const bf16x8*>(w2B + (ot * 4 + kb) * 512);
                cA2 = MFMA16(wa, H1A[kb], cA2);
                cB2 = MFMA16(wa, H1B[kb], cB2);
            }
            // lane (q,l15) reg r holds pre-act of h = ot*16 + q*4 + r, col l15
            f32x4 w3v = *reinterpret_cast<const f32x4*>(w3V + ot * 16);
#pragma unroll
            for (int r = 0; r < 4; ++r) {
                oA += sg(cA2[r]) * w3v[r];
                oB += sg(cB2[r]) * w3v[r];
            }
        }

        // cross-q reduce (cols split over 4 quarter-groups)
        oA += __shfl_xor(oA, 16);
        oA += __shfl_xor(oA, 32);
        oB += __shfl_xor(oB, 16);
        oB += __shfl_xor(oB, 32);

        if (q == 0) {   // col = l15
            float vA = oA + b3v;
            float vB = oB + b3v;
            const int bbA = cA * 16 + l15;
            const int bbB = cB * 16 + l15;
            if (transposed) {
                dst[(size_t)e * BATCH + bbA] = vA;
                dst[(size_t)e * BATCH + bbB] = vB;
            } else {
                dst[(size_t)bbA * E_CNT + e] = vA;
                dst[(size_t)bbB * E_CNT + e] = vB;
            }
        }
    }
}

// wsT[e][b] (256 x 8192) -> out[b][e] (8192 x 256), 64x64 LDS tiles
__global__ __launch_bounds__(256)
void transpose_out_kernel(const float* __restrict__ wsT, float* __restrict__ out)
{
    __shared__ float tile[64][65];
    const int tx = threadIdx.x & 63;
    const int ty = threadIdx.x >> 6;
    const int b0 = blockIdx.x * 64;
    const int e0 = blockIdx.y * 64;
#pragma unroll
    for (int r = ty; r < 64; r += 4)
        tile[r][tx] = wsT[(size_t)(e0 + r) * BATCH + b0 + tx];
    __syncthreads();
#pragma unroll
    for (int r = ty; r < 64; r += 4)
        out[(size_t)(b0 + r) * E_CNT + e0 + tx] = tile[tx][r];
}

extern "C" void kernel_launch(void* const* d_in, const int* in_sizes, int n_in,
                              void* d_out, int out_size, void* d_ws, size_t ws_size,
                              hipStream_t stream) {
    const float* x  = (const float*)d_in[0];
    const float* W1 = (const float*)d_in[1];
    const float* b1 = (const float*)d_in[2];
    const float* W2 = (const float*)d_in[3];
    const float* b2 = (const float*)d_in[4];
    const float* W3 = (const float*)d_in[5];
    const float* b3 = (const float*)d_in[6];
    float* out = (float*)d_out;

    const size_t XBF_BYTES = (size_t)BATCH * 16 * sizeof(unsigned short);  // 256 KB
    const size_t WST_BYTES = (size_t)E_CNT * BATCH * sizeof(float);        // 8 MB

    const bool have_xbf = ws_size >= XBF_BYTES + WST_BYTES;
    const bool have_wst = ws_size >= WST_BYTES;

    unsigned short* xbf = (unsigned short*)d_ws;
    float* wsT = have_xbf ? (float*)((char*)d_ws + XBF_BYTES) : (float*)d_ws;

    if (have_xbf)
        prep_x_kernel<<<dim3((BATCH * 16 + 255) / 256), dim3(256), 0, stream>>>(x, xbf);

    if (have_wst) {
        mlp256_kernel<<<dim3(E_CNT * BPE), dim3(256), 0, stream>>>(
            x, xbf, W1, b1, W2, b2, W3, b3, wsT, have_xbf ? 1 : 0, 1);
        transpose_out_kernel<<<dim3(BATCH / 64, E_CNT / 64), dim3(256), 0, stream>>>(
            wsT, out);
    } else {
        mlp256_kernel<<<dim3(E_CNT * BPE), dim3(256), 0, stream>>>(
            x, xbf, W1, b1, W2, b2, W3, b3, out, 0, 0);
    }
}